// Round 8
// baseline (84.736 us; speedup 1.0000x reference)
//
#include <hip/hip_runtime.h>

#define DEVINL __device__ __forceinline__

namespace {

constexpr int NB   = 4;
constexpr int CINv = 512;
constexpr int HIDv = 64;
constexpr int NCl  = 11;   // NC+1 output channels
constexpr int h1v = 60, w1v = 80;
constexpr int h2v = 30, w2v = 40;
constexpr int Hf = 480, Wf = 640;
constexpr int PPB1 = h1v * w1v;     // 4800 coarse px / batch
constexpr int PPB2 = h2v * w2v;     // 1200
constexpr int NP1 = NB * PPB1;      // 19200
constexpr int NP2 = NB * PPB2;      // 4800
constexpr int PPBF = Hf * Wf;       // 307200 fine px / batch
constexpr int NPF = NB * PPBF;      // 1228800
constexpr int NSHARD = 16;          // bbx accumulator shards

// workspace layout (float elements). 4 K-slices of partials per conv.
constexpr size_t WS_P1  = 0;                               // 4*64*19200
constexpr size_t WS_P2  = WS_P1 + 4ull * HIDv * NP1;       // 4*64*4800
constexpr size_t WS_Z   = WS_P2 + 4ull * HIDv * NP2;       // 4*11*4800
constexpr size_t WS_BBX = WS_Z + (size_t)NB * NCl * PPB1;  // 16 shards x 36 x 8 ints

// output layout (float elements)
constexpr size_t OUT_SEG = (size_t)NB * NCl * PPBF;  // 13,516,800
constexpr size_t OUT_BBX = OUT_SEG + (size_t)NPF;    // +1,228,800

DEVINL int iclamp(int v, int lo, int hi) { return v < lo ? lo : (v > hi ? hi : v); }

// ---------------------------------------------------------------------------
// Kernel 1: 1x1 convs as wave-independent K-split GEMM.  NO LDS, NO barriers.
// v4: TLP instead of ILP.  Rounds 5-7 showed hipcc pins 1-wave GEMM blocks to
// a 64-VGPR budget (max-occupancy heuristic; launch_bounds(64,4) ignored) and
// sinks prefetch loads to uses -> serial load-wait-use, and 1-wave workgroups
// under-fill CUs (occupancy 23%).  So: halve the wave tile to 128 px
// (2 px/lane float2), double waves to 6016, pack 4 og-waves of one
// (pxt,ks)-family per 256-thr block -> 1504 blocks = 5.9/CU = 23.5 waves/CU
// (73% occupancy, ~6/SIMD).  Aggregate issue (6 x ~160cyc/iter) > per-iter
// L2 latency (~500cyc) -> issue-bound; FMA-issue floor ~10us.
//   A: per-lane float2 global loads (L1/L2 served; family waves share slice).
//   W: uniform-address loads -> SGPR s_loads (og forced scalar via
//      readfirstlane).
// Sibling halves (og 0-3 / 4-7) of a family: bid and bid+752, 752%8==0 ->
// same XCD -> A reuse stays in one L2 (FETCH 25 MB < inputs confirms).
// ---------------------------------------------------------------------------
template <int PPB, int NPIX>
DEVINL void gemm_wave(const float* __restrict__ F, const float* __restrict__ Wm,
                      float* __restrict__ P, int pxt, int og, int ks) {
  const int lane = threadIdx.x & 63;
  const int gp0 = pxt * 128 + lane * 2;
  const int gpc = (gp0 <= NPIX - 2) ? gp0 : (NPIX - 2);   // conv2 tail clamp
  const int b = gpc / PPB, pb = gpc - b * PPB;            // 2-px never straddles batch
  const float* aB = F + ((size_t)b * CINv + ks * 128) * PPB + pb;
  const float* wB = Wm + (size_t)og * 8 * CINv + ks * 128;

  float acc[8][2];
#pragma unroll
  for (int j = 0; j < 8; ++j) { acc[j][0] = 0.f; acc[j][1] = 0.f; }

  float2 aP[2], aQ[2];
  float wP[2][8], wQ[2][8];

  // prologue: chunk 0 (cc 0,1) -> P buffers
  aP[0] = *reinterpret_cast<const float2*>(aB);
  aP[1] = *reinterpret_cast<const float2*>(aB + (size_t)PPB);
#pragma unroll
  for (int j = 0; j < 8; ++j) {
    wP[0][j] = wB[j * CINv + 0];
    wP[1][j] = wB[j * CINv + 1];
  }

  for (int k = 0; k < 64; k += 2) {
    const int cN = 2 * (k + 1);
    // prefetch chunks cN, cN+1 -> Q
    aQ[0] = *reinterpret_cast<const float2*>(aB + (size_t)cN * PPB);
    aQ[1] = *reinterpret_cast<const float2*>(aB + (size_t)(cN + 1) * PPB);
#pragma unroll
    for (int j = 0; j < 8; ++j) {
      wQ[0][j] = wB[j * CINv + cN + 0];
      wQ[1][j] = wB[j * CINv + cN + 1];
    }
#pragma unroll
    for (int c = 0; c < 2; ++c) {
      const float2 av = aP[c];
#pragma unroll
      for (int j = 0; j < 8; ++j) {
        const float wv = wP[c][j];
        acc[j][0] = fmaf(av.x, wv, acc[j][0]);
        acc[j][1] = fmaf(av.y, wv, acc[j][1]);
      }
    }
    if (k + 2 < 64) {   // prefetch next pair -> P
      const int cM = 2 * (k + 2);
      aP[0] = *reinterpret_cast<const float2*>(aB + (size_t)cM * PPB);
      aP[1] = *reinterpret_cast<const float2*>(aB + (size_t)(cM + 1) * PPB);
#pragma unroll
      for (int j = 0; j < 8; ++j) {
        wP[0][j] = wB[j * CINv + cM + 0];
        wP[1][j] = wB[j * CINv + cM + 1];
      }
    }
#pragma unroll
    for (int c = 0; c < 2; ++c) {
      const float2 av = aQ[c];
#pragma unroll
      for (int j = 0; j < 8; ++j) {
        const float wv = wQ[c][j];
        acc[j][0] = fmaf(av.x, wv, acc[j][0]);
        acc[j][1] = fmaf(av.y, wv, acc[j][1]);
      }
    }
  }

  if (gp0 <= NPIX - 2) {
#pragma unroll
    for (int j = 0; j < 8; ++j) {
      float2 v;
      v.x = acc[j][0]; v.y = acc[j][1];
      *reinterpret_cast<float2*>(P + (size_t)(ks * 64 + og * 8 + j) * NPIX + gp0) = v;
    }
  }
}

__global__ __launch_bounds__(256) void k_gemm(const float* __restrict__ f1,
                                              const float* __restrict__ f2,
                                              const float* __restrict__ w1,
                                              const float* __restrict__ w2,
                                              float* __restrict__ ws) {
  // bid = half*752 + f ; block = waves og {half*4 .. half*4+3} of family f.
  const int bid = blockIdx.x;          // 0..1503
  const int half = bid / 752;          // 0..1
  const int f = bid - half * 752;      // 0..751
  const int og = __builtin_amdgcn_readfirstlane(half * 4 + (threadIdx.x >> 6));

  if (f < 600) {
    gemm_wave<PPB1, NP1>(f1, w1, ws + WS_P1, f >> 2, og, f & 3);
  } else {
    const int g = f - 600;             // 0..151  (38 px-tiles x 4 ks)
    gemm_wave<PPB2, NP2>(f2, w2, ws + WS_P2, g >> 2, og, g & 3);
  }
}

// ---------------------------------------------------------------------------
// Kernel 2: sum 4 K-slices -> relu+bias, add x2-upsampled branch2 (slice-
// summed at the 4 taps), then 64->11 GEMM per pixel -> z (coarse logits).
// Grid: 600 blocks x 256 thr; 32 px per block; thread = (px, channel-octet).
// Block 0 also inits the bbx shard accumulators (runs before k_up_softmax).
// ---------------------------------------------------------------------------
__global__ __launch_bounds__(256) void k_combine_z(float* __restrict__ ws,
                                                   const float* __restrict__ b1,
                                                   const float* __restrict__ b2,
                                                   const float* __restrict__ w3,
                                                   const float* __restrict__ b3) {
  __shared__ float inter[64 * 32];  // [ch][px]
  __shared__ float w3s[NCl * HIDv];
  const int t = threadIdx.x;

  if (blockIdx.x == 0) {  // init bbx shards: 16*36 entries x 8 ints
    int* sh = (int*)(ws + WS_BBX);
    for (int i = t; i < NSHARD * 36 * 8; i += 256) {
      int f = i & 7;
      sh[i] = (f == 0 || f >= 5) ? 0
            : ((f == 1 || f == 3) ? 0x7fffffff : (int)0x80000000);
    }
  }
  for (int e = t; e < NCl * HIDv; e += 256) w3s[e] = w3[e];

  const int pxl = t & 31;
  const int qi = t >> 5;  // 0..7, 8 channels each
  const int gp = blockIdx.x * 32 + pxl;
  const int b = gp / PPB1, pb = gp - b * PPB1;
  const int y = pb / w1v, x = pb - y * w1v;

  // x2 bilinear (half-pixel, edge clamp)
  const float sx = x * 0.5f - 0.25f;
  const float x0f = floorf(sx);
  const float fx = sx - x0f;
  const int ix0 = iclamp((int)x0f, 0, w2v - 1);
  const int ix1 = iclamp((int)x0f + 1, 0, w2v - 1);
  const float sy = y * 0.5f - 0.25f;
  const float y0f = floorf(sy);
  const float fy = sy - y0f;
  const int iy0 = iclamp((int)y0f, 0, h2v - 1);
  const int iy1 = iclamp((int)y0f + 1, 0, h2v - 1);

  const float* p1 = ws + WS_P1;
  const float* p2 = ws + WS_P2;
  const int base2 = b * PPB2;
  const int i00 = base2 + iy0 * w2v + ix0;
  const int i01 = base2 + iy0 * w2v + ix1;
  const int i10 = base2 + iy1 * w2v + ix0;
  const int i11 = base2 + iy1 * w2v + ix1;

#pragma unroll
  for (int cc = 0; cc < 8; ++cc) {
    const int ch = qi * 8 + cc;
    float v = b1[ch];
#pragma unroll
    for (int s = 0; s < 4; ++s)
      v += p1[(size_t)(s * 64 + ch) * NP1 + gp];
    v = fmaxf(v, 0.f);
    float t00 = b2[ch], t01 = t00, t10 = t00, t11 = t00;
#pragma unroll
    for (int s = 0; s < 4; ++s) {
      const float* ps = p2 + (size_t)(s * 64 + ch) * NP2;
      t00 += ps[i00]; t01 += ps[i01]; t10 += ps[i10]; t11 += ps[i11];
    }
    const float v00 = fmaxf(t00, 0.f), v01 = fmaxf(t01, 0.f);
    const float v10 = fmaxf(t10, 0.f), v11 = fmaxf(t11, 0.f);
    const float top = v00 + fx * (v01 - v00);
    const float bot = v10 + fx * (v11 - v10);
    v += top + fy * (bot - top);
    inter[ch * 32 + pxl] = v;
  }
  __syncthreads();

  // z = W3 * inter + b3: out o = qi, plus o = qi+8 for qi < 3
  float* z = ws + WS_Z;
  {
    float a = b3[qi];
#pragma unroll
    for (int ch = 0; ch < 64; ++ch)
      a = fmaf(inter[ch * 32 + pxl], w3s[qi * HIDv + ch], a);
    z[((size_t)b * NCl + qi) * PPB1 + pb] = a;
  }
  if (qi < 3) {
    const int o = qi + 8;
    float a = b3[o];
#pragma unroll
    for (int ch = 0; ch < 64; ++ch)
      a = fmaf(inter[ch * 32 + pxl], w3s[o * HIDv + ch], a);
    z[((size_t)b * NCl + o) * PPB1 + pb] = a;
  }
}

// ---------------------------------------------------------------------------
// Kernel 3: x8 bilinear of z + relu + softmax + argmax + in-wave ballot bbx.
// Block = 128x2 fine tile, grid 4800; 1 px/thread (lg[11] stays in regs).
// ---------------------------------------------------------------------------
__global__ __launch_bounds__(256) void k_up_softmax(const float* __restrict__ ws,
                                                    float* __restrict__ out,
                                                    int* __restrict__ shards) {
  constexpr int ZR = 3, ZC = 18, ZN = NCl * ZR * ZC;  // 594
  __shared__ float zt[ZN];
  __shared__ int sB[4][9][4];
  const int t = threadIdx.x;
  const int tile = blockIdx.x;
  const int tx = tile % 5;
  const int ty = (tile / 5) % 240;
  const int b  = tile / 1200;
  const int base_x = tx * 16 - 1;
  const int row0 = ty * 2;
  const int base_y = (int)floorf((row0 + 0.5f) * 0.125f - 0.5f);

  // stage z tile (edge-clamped)
  const float* zb = ws + WS_Z + (size_t)b * NCl * PPB1;
  for (int e = t; e < ZN; e += 256) {
    int ch = e / (ZR * ZC);
    int rc = e % (ZR * ZC);
    int row = rc / ZC, col = rc % ZC;
    int gr = iclamp(base_y + row, 0, h1v - 1);
    int gc = iclamp(base_x + col, 0, w1v - 1);
    zt[e] = zb[(size_t)ch * PPB1 + gr * w1v + gc];
  }
  __syncthreads();

  const int x  = t & 127;
  const int rr = t >> 7;
  const int X = tx * 128 + x;
  const int Y = row0 + rr;

  const float sy = (Y + 0.5f) * 0.125f - 0.5f;
  const int y0g = (int)floorf(sy);
  const float fy = sy - (float)y0g;
  const int lry = y0g - base_y;                       // 0 or 1
  const int lcx = (2 * x + 9) >> 4;                   // 0..16
  const float fx = (float)(2 * x - 7) * 0.0625f + 1.0f - (float)lcx;

  float lg[NCl];
  float m = -1.f;
  int bi = 0;
#pragma unroll
  for (int c = 0; c < NCl; ++c) {
    const int base = c * (ZR * ZC) + lry * ZC + lcx;
    float v00 = zt[base],      v01 = zt[base + 1];
    float v10 = zt[base + ZC], v11 = zt[base + ZC + 1];
    float l0 = v00 + fy * (v10 - v00);
    float l1 = v01 + fy * (v11 - v01);
    float v = fmaxf(l0 + fx * (l1 - l0), 0.f);        // relu(logit)
    lg[c] = v;
    if (v > m) { m = v; bi = c; }                     // first-index tiebreak
  }

  float s = 0.f;
#pragma unroll
  for (int c = 0; c < NCl; ++c) {
    float e = __expf(lg[c] - m);
    lg[c] = e;
    s += e;
  }
  const float inv = __builtin_amdgcn_rcpf(s);

  const size_t r = (size_t)Y * Wf + X;
  float* prob = out + (size_t)b * NCl * PPBF;
#pragma unroll
  for (int c = 0; c < NCl; ++c)
    prob[(size_t)c * PPBF + r] = lg[c] * inv;
  out[OUT_SEG + (size_t)b * PPBF + r] = (float)bi;

  // --- bbx via wave ballot (wave = 64 contiguous x in row Y) ---
  const int lane = t & 63;
  const int wv = t >> 6;
  int cw[9], xn[9], xx[9];
#pragma unroll
  for (int c = 1; c <= 9; ++c) {
    unsigned long long msk = __ballot(bi == c);
    cw[c - 1] = (int)__popcll(msk);
    xn[c - 1] = msk ? (int)__builtin_ctzll(msk) : 0;
    xx[c - 1] = msk ? 63 - (int)__builtin_clzll(msk) : 0;
  }
  if (lane == 0) {   // lane0's X is the wave's base x
#pragma unroll
    for (int c = 0; c < 9; ++c) {
      sB[wv][c][0] = cw[c];
      sB[wv][c][1] = X + xn[c];
      sB[wv][c][2] = X + xx[c];
      sB[wv][c][3] = Y;
    }
  }
  __syncthreads();
  if (t < 9) {
    int C = 0, mn = 0x7fffffff, mx = -1, yn = 0x7fffffff, yx = -1;
#pragma unroll
    for (int w2 = 0; w2 < 4; ++w2) {
      int cc = sB[w2][t][0];
      if (cc) {
        C += cc;
        mn = min(mn, sB[w2][t][1]); mx = max(mx, sB[w2][t][2]);
        yn = min(yn, sB[w2][t][3]); yx = max(yx, sB[w2][t][3]);
      }
    }
    if (C) {
      int* e = shards + (((tile & (NSHARD - 1)) * 36) + b * 9 + t) * 8;
      atomicAdd(e + 0, C);
      atomicMin(e + 1, mn);
      atomicMax(e + 2, mx);
      atomicMin(e + 3, yn);
      atomicMax(e + 4, yx);
    }
  }
}

// ---------------------------------------------------------------------------
// Kernel 4: reduce shards, finalize bbx rows (36 x 6), THRESH = 100.
// ---------------------------------------------------------------------------
__global__ void k_bbx_final(const int* __restrict__ sh, float* __restrict__ out) {
  const int t = threadIdx.x;
  if (t >= 36) return;
  int C = 0, xn = 0x7fffffff, xx = -1, yn = 0x7fffffff, yx = -1;
  for (int s = 0; s < NSHARD; ++s) {
    const int* e = sh + (s * 36 + t) * 8;
    int c = e[0];
    if (c) {
      C += c;
      xn = min(xn, e[1]); xx = max(xx, e[2]);
      yn = min(yn, e[3]); yx = max(yx, e[4]);
    }
  }
  float* o = out + OUT_BBX + t * 6;
  if (C >= 100) {
    o[0] = (float)(t / 9);
    o[1] = (float)xn;
    o[2] = (float)yn;
    o[3] = (float)xx;
    o[4] = (float)yx;
    o[5] = (float)(t % 9 + 1);
  } else {
    for (int i = 0; i < 6; ++i) o[i] = -1.f;
  }
}

}  // namespace

extern "C" void kernel_launch(void* const* d_in, const int* in_sizes, int n_in,
                              void* d_out, int out_size, void* d_ws, size_t ws_size,
                              hipStream_t stream) {
  const float* f1 = (const float*)d_in[0];
  const float* f2 = (const float*)d_in[1];
  const float* w1 = (const float*)d_in[2];
  const float* b1 = (const float*)d_in[3];
  const float* w2 = (const float*)d_in[4];
  const float* b2 = (const float*)d_in[5];
  const float* w3 = (const float*)d_in[6];
  const float* b3 = (const float*)d_in[7];
  float* out = (float*)d_out;
  float* ws = (float*)d_ws;

  hipLaunchKernelGGL(k_gemm, dim3(1504), dim3(256), 0, stream, f1, f2, w1, w2, ws);
  hipLaunchKernelGGL(k_combine_z, dim3(600), dim3(256), 0, stream, ws, b1, b2, w3, b3);
  hipLaunchKernelGGL(k_up_softmax, dim3(4800), dim3(256), 0, stream, ws, out,
                     (int*)(ws + WS_BBX));
  hipLaunchKernelGGL(k_bbx_final, dim3(1), dim3(64), 0, stream,
                     (const int*)(ws + WS_BBX), out);
}

// Round 9
// 84.454 us; speedup vs baseline: 1.0033x; 1.0033x over previous
//
#include <hip/hip_runtime.h>

#define DEVINL __device__ __forceinline__

namespace {

constexpr int NB   = 4;
constexpr int CINv = 512;
constexpr int HIDv = 64;
constexpr int NCl  = 11;   // NC+1 output channels
constexpr int h1v = 60, w1v = 80;
constexpr int h2v = 30, w2v = 40;
constexpr int Hf = 480, Wf = 640;
constexpr int PPB1 = h1v * w1v;     // 4800 coarse px / batch
constexpr int PPB2 = h2v * w2v;     // 1200
constexpr int NP1 = NB * PPB1;      // 19200
constexpr int NP2 = NB * PPB2;      // 4800
constexpr int PPBF = Hf * Wf;       // 307200 fine px / batch
constexpr int NPF = NB * PPBF;      // 1228800
constexpr int NSHARD = 64;          // bbx accumulator shards

// workspace layout (float elements). 4 K-slices of partials per conv.
constexpr size_t WS_P1  = 0;                               // 4*64*19200
constexpr size_t WS_P2  = WS_P1 + 4ull * HIDv * NP1;       // 4*64*4800
constexpr size_t WS_Z   = WS_P2 + 4ull * HIDv * NP2;       // 4*11*4800
constexpr size_t WS_BBX = WS_Z + (size_t)NB * NCl * PPB1;  // 64 shards x 36 x 8 ints

// output layout (float elements)
constexpr size_t OUT_SEG = (size_t)NB * NCl * PPBF;  // 13,516,800
constexpr size_t OUT_BBX = OUT_SEG + (size_t)NPF;    // +1,228,800

DEVINL int iclamp(int v, int lo, int hi) { return v < lo ? lo : (v > hi ? hi : v); }

// ---------------------------------------------------------------------------
// Kernel 1: 1x1 convs as wave-independent K-split GEMM.  NO LDS, NO barriers.
// v5: sched_barrier-enforced software pipeline.  Rounds 5-8 proved hipcc's
// scheduler sinks prefetch loads to their uses (VGPR 20-32, serial
// load-wait-use, VALUBusy pinned ~26%) regardless of launch_bounds.
// __builtin_amdgcn_sched_barrier(0) forbids reordering across it:
//   { issue next chunk loads } SCHED_BARRIER { 64 FMAs on current chunk }
// so the load dest regs stay live (double buffer materializes) and the
// auto-waitcnt at first use is a partial wait with a full compute phase of
// latency in flight.  K-chunk = 4: W reads are uniform float4 (s_load_dwordx4
// candidates), A is float2/lane.  TLP backstop kept: 6016 waves in 1504
// 256-thr blocks = 5.9 blocks/CU (~6 waves/SIMD).
// Family = (pxt,ks) of 128 px x 128 K; 8 og-waves share its A-slice; halves
// live at bid f and f+752 (752%8==0 -> same XCD L2).
// ---------------------------------------------------------------------------
template <int PPB, int NPIX>
DEVINL void gemm_wave(const float* __restrict__ F, const float* __restrict__ Wm,
                      float* __restrict__ P, int pxt, int og, int ks) {
  const int lane = threadIdx.x & 63;
  const int gp0 = pxt * 128 + lane * 2;
  const int gpc = (gp0 <= NPIX - 2) ? gp0 : (NPIX - 2);   // conv2 tail clamp
  const int b = gpc / PPB, pb = gpc - b * PPB;            // 2-px never straddles batch
  const float* aB = F + ((size_t)b * CINv + ks * 128) * PPB + pb;
  const float* wB = Wm + (size_t)og * 8 * CINv + ks * 128;

  float acc[8][2];
#pragma unroll
  for (int j = 0; j < 8; ++j) { acc[j][0] = 0.f; acc[j][1] = 0.f; }

  float2 aX[4], aY[4];     // A double buffer: 4 K-values x 2 px
  float4 wX[8], wY[8];     // W double buffer: 8 outs x 4 K (uniform loads)

#define ISSUE_A(buf, c)                                                       \
  _Pragma("unroll")                                                           \
  for (int i = 0; i < 4; ++i)                                                 \
    buf[i] = *reinterpret_cast<const float2*>(aB + (size_t)((c) + i) * PPB);

#define ISSUE_W(buf, c)                                                       \
  _Pragma("unroll")                                                           \
  for (int j = 0; j < 8; ++j)                                                 \
    buf[j] = *reinterpret_cast<const float4*>(wB + j * CINv + (c));

#define COMPUTE(ab, wb)                                                       \
  _Pragma("unroll")                                                           \
  for (int j = 0; j < 8; ++j) {                                               \
    acc[j][0] = fmaf(ab[0].x, wb[j].x, acc[j][0]);                            \
    acc[j][1] = fmaf(ab[0].y, wb[j].x, acc[j][1]);                            \
    acc[j][0] = fmaf(ab[1].x, wb[j].y, acc[j][0]);                            \
    acc[j][1] = fmaf(ab[1].y, wb[j].y, acc[j][1]);                            \
    acc[j][0] = fmaf(ab[2].x, wb[j].z, acc[j][0]);                            \
    acc[j][1] = fmaf(ab[2].y, wb[j].z, acc[j][1]);                            \
    acc[j][0] = fmaf(ab[3].x, wb[j].w, acc[j][0]);                            \
    acc[j][1] = fmaf(ab[3].y, wb[j].w, acc[j][1]);                            \
  }

  // prologue: chunk 0 -> X
  ISSUE_A(aX, 0)
  ISSUE_W(wX, 0)
  for (int c = 0; c < 128; c += 8) {
    // prefetch chunk c+4 -> Y, then compute chunk c from X
    ISSUE_A(aY, c + 4)
    ISSUE_W(wY, c + 4)
    __builtin_amdgcn_sched_barrier(0);
    COMPUTE(aX, wX)
    // prefetch chunk c+8 -> X, then compute chunk c+4 from Y
    if (c + 8 < 128) {
      ISSUE_A(aX, c + 8)
      ISSUE_W(wX, c + 8)
    }
    __builtin_amdgcn_sched_barrier(0);
    COMPUTE(aY, wY)
  }
#undef ISSUE_A
#undef ISSUE_W
#undef COMPUTE

  if (gp0 <= NPIX - 2) {
#pragma unroll
    for (int j = 0; j < 8; ++j) {
      float2 v;
      v.x = acc[j][0]; v.y = acc[j][1];
      *reinterpret_cast<float2*>(P + (size_t)(ks * 64 + og * 8 + j) * NPIX + gp0) = v;
    }
  }
}

__global__ __launch_bounds__(256) void k_gemm(const float* __restrict__ f1,
                                              const float* __restrict__ f2,
                                              const float* __restrict__ w1,
                                              const float* __restrict__ w2,
                                              float* __restrict__ ws) {
  // bid = q*752 + f ; block = waves og {q*4 .. q*4+3} of family f.
  const int bid = blockIdx.x;          // 0..1503
  const int q = bid / 752;             // 0..1
  const int f = bid - q * 752;         // 0..751
  const int og = __builtin_amdgcn_readfirstlane(q * 4 + (threadIdx.x >> 6));

  if (f < 600) {
    gemm_wave<PPB1, NP1>(f1, w1, ws + WS_P1, f >> 2, og, f & 3);
  } else {
    const int g = f - 600;             // 0..151  (38 px-tiles x 4 ks)
    gemm_wave<PPB2, NP2>(f2, w2, ws + WS_P2, g >> 2, og, g & 3);
  }
}

// ---------------------------------------------------------------------------
// Kernel 2: sum 4 K-slices -> relu+bias, add x2-upsampled branch2 (slice-
// summed at the 4 taps), then 64->11 GEMM per pixel -> z (coarse logits).
// Grid: 600 blocks x 256 thr; 32 px per block; thread = (px, channel-octet).
// Block 0 also inits the bbx shard accumulators (runs before k_up_softmax).
// ---------------------------------------------------------------------------
__global__ __launch_bounds__(256) void k_combine_z(float* __restrict__ ws,
                                                   const float* __restrict__ b1,
                                                   const float* __restrict__ b2,
                                                   const float* __restrict__ w3,
                                                   const float* __restrict__ b3) {
  __shared__ float inter[64 * 32];  // [ch][px]
  __shared__ float w3s[NCl * HIDv];
  const int t = threadIdx.x;

  if (blockIdx.x == 0) {  // init bbx shards: 64*36 entries x 8 ints
    int* sh = (int*)(ws + WS_BBX);
    for (int i = t; i < NSHARD * 36 * 8; i += 256) {
      int f = i & 7;
      sh[i] = (f == 0 || f >= 5) ? 0
            : ((f == 1 || f == 3) ? 0x7fffffff : (int)0x80000000);
    }
  }
  for (int e = t; e < NCl * HIDv; e += 256) w3s[e] = w3[e];

  const int pxl = t & 31;
  const int qi = t >> 5;  // 0..7, 8 channels each
  const int gp = blockIdx.x * 32 + pxl;
  const int b = gp / PPB1, pb = gp - b * PPB1;
  const int y = pb / w1v, x = pb - y * w1v;

  // x2 bilinear (half-pixel, edge clamp)
  const float sx = x * 0.5f - 0.25f;
  const float x0f = floorf(sx);
  const float fx = sx - x0f;
  const int ix0 = iclamp((int)x0f, 0, w2v - 1);
  const int ix1 = iclamp((int)x0f + 1, 0, w2v - 1);
  const float sy = y * 0.5f - 0.25f;
  const float y0f = floorf(sy);
  const float fy = sy - y0f;
  const int iy0 = iclamp((int)y0f, 0, h2v - 1);
  const int iy1 = iclamp((int)y0f + 1, 0, h2v - 1);

  const float* p1 = ws + WS_P1;
  const float* p2 = ws + WS_P2;
  const int base2 = b * PPB2;
  const int i00 = base2 + iy0 * w2v + ix0;
  const int i01 = base2 + iy0 * w2v + ix1;
  const int i10 = base2 + iy1 * w2v + ix0;
  const int i11 = base2 + iy1 * w2v + ix1;

#pragma unroll
  for (int cc = 0; cc < 8; ++cc) {
    const int ch = qi * 8 + cc;
    float v = b1[ch];
#pragma unroll
    for (int s = 0; s < 4; ++s)
      v += p1[(size_t)(s * 64 + ch) * NP1 + gp];
    v = fmaxf(v, 0.f);
    float t00 = b2[ch], t01 = t00, t10 = t00, t11 = t00;
#pragma unroll
    for (int s = 0; s < 4; ++s) {
      const float* ps = p2 + (size_t)(s * 64 + ch) * NP2;
      t00 += ps[i00]; t01 += ps[i01]; t10 += ps[i10]; t11 += ps[i11];
    }
    const float v00 = fmaxf(t00, 0.f), v01 = fmaxf(t01, 0.f);
    const float v10 = fmaxf(t10, 0.f), v11 = fmaxf(t11, 0.f);
    const float top = v00 + fx * (v01 - v00);
    const float bot = v10 + fx * (v11 - v10);
    v += top + fy * (bot - top);
    inter[ch * 32 + pxl] = v;
  }
  __syncthreads();

  // z = W3 * inter + b3: out o = qi, plus o = qi+8 for qi < 3
  float* z = ws + WS_Z;
  {
    float a = b3[qi];
#pragma unroll
    for (int ch = 0; ch < 64; ++ch)
      a = fmaf(inter[ch * 32 + pxl], w3s[qi * HIDv + ch], a);
    z[((size_t)b * NCl + qi) * PPB1 + pb] = a;
  }
  if (qi < 3) {
    const int o = qi + 8;
    float a = b3[o];
#pragma unroll
    for (int ch = 0; ch < 64; ++ch)
      a = fmaf(inter[ch * 32 + pxl], w3s[o * HIDv + ch], a);
    z[((size_t)b * NCl + o) * PPB1 + pb] = a;
  }
}

// ---------------------------------------------------------------------------
// Kernel 3: x8 bilinear of z + relu + softmax + argmax + in-wave ballot bbx.
// Block = 128x2 fine tile, grid 4800; 1 px/thread (lg[11] stays in regs).
// ---------------------------------------------------------------------------
__global__ __launch_bounds__(256) void k_up_softmax(const float* __restrict__ ws,
                                                    float* __restrict__ out,
                                                    int* __restrict__ shards) {
  constexpr int ZR = 3, ZC = 18, ZN = NCl * ZR * ZC;  // 594
  __shared__ float zt[ZN];
  __shared__ int sB[4][9][4];
  const int t = threadIdx.x;
  const int tile = blockIdx.x;
  const int tx = tile % 5;
  const int ty = (tile / 5) % 240;
  const int b  = tile / 1200;
  const int base_x = tx * 16 - 1;
  const int row0 = ty * 2;
  const int base_y = (int)floorf((row0 + 0.5f) * 0.125f - 0.5f);

  // stage z tile (edge-clamped)
  const float* zb = ws + WS_Z + (size_t)b * NCl * PPB1;
  for (int e = t; e < ZN; e += 256) {
    int ch = e / (ZR * ZC);
    int rc = e % (ZR * ZC);
    int row = rc / ZC, col = rc % ZC;
    int gr = iclamp(base_y + row, 0, h1v - 1);
    int gc = iclamp(base_x + col, 0, w1v - 1);
    zt[e] = zb[(size_t)ch * PPB1 + gr * w1v + gc];
  }
  __syncthreads();

  const int x  = t & 127;
  const int rr = t >> 7;
  const int X = tx * 128 + x;
  const int Y = row0 + rr;

  const float sy = (Y + 0.5f) * 0.125f - 0.5f;
  const int y0g = (int)floorf(sy);
  const float fy = sy - (float)y0g;
  const int lry = y0g - base_y;                       // 0 or 1
  const int lcx = (2 * x + 9) >> 4;                   // 0..16
  const float fx = (float)(2 * x - 7) * 0.0625f + 1.0f - (float)lcx;

  float lg[NCl];
  float m = -1.f;
  int bi = 0;
#pragma unroll
  for (int c = 0; c < NCl; ++c) {
    const int base = c * (ZR * ZC) + lry * ZC + lcx;
    float v00 = zt[base],      v01 = zt[base + 1];
    float v10 = zt[base + ZC], v11 = zt[base + ZC + 1];
    float l0 = v00 + fy * (v10 - v00);
    float l1 = v01 + fy * (v11 - v01);
    float v = fmaxf(l0 + fx * (l1 - l0), 0.f);        // relu(logit)
    lg[c] = v;
    if (v > m) { m = v; bi = c; }                     // first-index tiebreak
  }

  float s = 0.f;
#pragma unroll
  for (int c = 0; c < NCl; ++c) {
    float e = __expf(lg[c] - m);
    lg[c] = e;
    s += e;
  }
  const float inv = __builtin_amdgcn_rcpf(s);

  const size_t r = (size_t)Y * Wf + X;
  float* prob = out + (size_t)b * NCl * PPBF;
#pragma unroll
  for (int c = 0; c < NCl; ++c)
    prob[(size_t)c * PPBF + r] = lg[c] * inv;
  out[OUT_SEG + (size_t)b * PPBF + r] = (float)bi;

  // --- bbx via wave ballot (wave = 64 contiguous x in row Y) ---
  const int lane = t & 63;
  const int wv = t >> 6;
  int cw[9], xn[9], xx[9];
#pragma unroll
  for (int c = 1; c <= 9; ++c) {
    unsigned long long msk = __ballot(bi == c);
    cw[c - 1] = (int)__popcll(msk);
    xn[c - 1] = msk ? (int)__builtin_ctzll(msk) : 0;
    xx[c - 1] = msk ? 63 - (int)__builtin_clzll(msk) : 0;
  }
  if (lane == 0) {   // lane0's X is the wave's base x
#pragma unroll
    for (int c = 0; c < 9; ++c) {
      sB[wv][c][0] = cw[c];
      sB[wv][c][1] = X + xn[c];
      sB[wv][c][2] = X + xx[c];
      sB[wv][c][3] = Y;
    }
  }
  __syncthreads();
  if (t < 9) {
    int C = 0, mn = 0x7fffffff, mx = -1, yn = 0x7fffffff, yx = -1;
#pragma unroll
    for (int w2 = 0; w2 < 4; ++w2) {
      int cc = sB[w2][t][0];
      if (cc) {
        C += cc;
        mn = min(mn, sB[w2][t][1]); mx = max(mx, sB[w2][t][2]);
        yn = min(yn, sB[w2][t][3]); yx = max(yx, sB[w2][t][3]);
      }
    }
    if (C) {
      int* e = shards + (((tile & (NSHARD - 1)) * 36) + b * 9 + t) * 8;
      atomicAdd(e + 0, C);
      atomicMin(e + 1, mn);
      atomicMax(e + 2, mx);
      atomicMin(e + 3, yn);
      atomicMax(e + 4, yx);
    }
  }
}

// ---------------------------------------------------------------------------
// Kernel 4: reduce shards, finalize bbx rows (36 x 6), THRESH = 100.
// ---------------------------------------------------------------------------
__global__ void k_bbx_final(const int* __restrict__ sh, float* __restrict__ out) {
  const int t = threadIdx.x;
  if (t >= 36) return;
  int C = 0, xn = 0x7fffffff, xx = -1, yn = 0x7fffffff, yx = -1;
  for (int s = 0; s < NSHARD; ++s) {
    const int* e = sh + (s * 36 + t) * 8;
    int c = e[0];
    if (c) {
      C += c;
      xn = min(xn, e[1]); xx = max(xx, e[2]);
      yn = min(yn, e[3]); yx = max(yx, e[4]);
    }
  }
  float* o = out + OUT_BBX + t * 6;
  if (C >= 100) {
    o[0] = (float)(t / 9);
    o[1] = (float)xn;
    o[2] = (float)yn;
    o[3] = (float)xx;
    o[4] = (float)yx;
    o[5] = (float)(t % 9 + 1);
  } else {
    for (int i = 0; i < 6; ++i) o[i] = -1.f;
  }
}

}  // namespace

extern "C" void kernel_launch(void* const* d_in, const int* in_sizes, int n_in,
                              void* d_out, int out_size, void* d_ws, size_t ws_size,
                              hipStream_t stream) {
  const float* f1 = (const float*)d_in[0];
  const float* f2 = (const float*)d_in[1];
  const float* w1 = (const float*)d_in[2];
  const float* b1 = (const float*)d_in[3];
  const float* w2 = (const float*)d_in[4];
  const float* b2 = (const float*)d_in[5];
  const float* w3 = (const float*)d_in[6];
  const float* b3 = (const float*)d_in[7];
  float* out = (float*)d_out;
  float* ws = (float*)d_ws;

  hipLaunchKernelGGL(k_gemm, dim3(1504), dim3(256), 0, stream, f1, f2, w1, w2, ws);
  hipLaunchKernelGGL(k_combine_z, dim3(600), dim3(256), 0, stream, ws, b1, b2, w3, b3);
  hipLaunchKernelGGL(k_up_softmax, dim3(4800), dim3(256), 0, stream, ws, out,
                     (int*)(ws + WS_BBX));
  hipLaunchKernelGGL(k_bbx_final, dim3(1), dim3(64), 0, stream,
                     (const int*)(ws + WS_BBX), out);
}

// Round 10
// 79.172 us; speedup vs baseline: 1.0703x; 1.0667x over previous
//
#include <hip/hip_runtime.h>

#define DEVINL __device__ __forceinline__

namespace {

constexpr int NB   = 4;
constexpr int CINv = 512;
constexpr int HIDv = 64;
constexpr int NCl  = 11;   // NC+1 output channels
constexpr int h1v = 60, w1v = 80;
constexpr int h2v = 30, w2v = 40;
constexpr int Hf = 480, Wf = 640;
constexpr int PPB1 = h1v * w1v;     // 4800 coarse px / batch
constexpr int PPB2 = h2v * w2v;     // 1200
constexpr int NP1 = NB * PPB1;      // 19200
constexpr int NP2 = NB * PPB2;      // 4800
constexpr int PPBF = Hf * Wf;       // 307200 fine px / batch
constexpr int NPF = NB * PPBF;      // 1228800
constexpr int NSHARD = 64;          // bbx accumulator shards

// workspace layout (float elements). 4 K-slices of partials per conv.
constexpr size_t WS_P1  = 0;                               // 4*64*19200
constexpr size_t WS_P2  = WS_P1 + 4ull * HIDv * NP1;       // 4*64*4800
constexpr size_t WS_Z   = WS_P2 + 4ull * HIDv * NP2;       // 4*11*4800
constexpr size_t WS_BBX = WS_Z + (size_t)NB * NCl * PPB1;  // 64 shards x 36 x 8 ints

// output layout (float elements)
constexpr size_t OUT_SEG = (size_t)NB * NCl * PPBF;  // 13,516,800
constexpr size_t OUT_BBX = OUT_SEG + (size_t)NPF;    // +1,228,800

DEVINL int iclamp(int v, int lo, int hi) { return v < lo ? lo : (v > hi ? hi : v); }

DEVINL void async_copy16(const float* g_src, float* lds_dst) {
  __builtin_amdgcn_global_load_lds(
      (const __attribute__((address_space(1))) unsigned int*)g_src,
      (__attribute__((address_space(3))) unsigned int*)lds_dst, 16, 0, 0);
}

// ---------------------------------------------------------------------------
// Kernel 1: 1x1 convs, K-split GEMM.  v6: LDS-staged A via global_load_lds
// (async DMA, ZERO dest VGPRs -- rounds 5-9 proved hipcc never keeps
// register prefetch buffers live: VGPR 20-32, serial load-wait-use,
// VALUBusy pinned ~26-30% across launch_bounds/sched_barrier variants).
// T3 2-phase recipe: { STAGE(next buf) ; compute(cur buf) ; barrier } --
// stage latency hides under the 256-FMA/thread compute phase; barrier's
// vmcnt(0) drain is the only sync.
// Block = 256 thr (4 waves) = 128 px x 32 outs x 128 K-slice; BK=16.
//   A: [cc][128 px] in LDS (8 KB x 2 bufs); ds_read_b64 at lane*8B ->
//      conflict-free (round-4's 1.15M conflicts came from its layout).
//   W: uniform s_load (og/wave readfirstlane'd), consumed inline -- never
//      register-staged (round-4's VGPR=256 came from W reg-buffers).
// LDS bytes/FMA = 0.5 -> 64 B/cyc/CU at full VALU, under the 85 B/cyc b128
// budget (the classic-LDS-GEMM killer).  Grid 1504 = 5.9 blocks/CU (23.5
// waves/CU); A-sharing ogg-pair at bid f / f+752 (752%8==0 -> same XCD L2).
// ---------------------------------------------------------------------------
template <int PPB, int NPIX>
DEVINL void gemm_tile(const float* __restrict__ F, const float* __restrict__ Wm,
                      float* __restrict__ P, int pxt, int ogg, int ks,
                      float* __restrict__ Abuf /* [2][2048] floats */) {
  const int t = threadIdx.x;
  const int lane = t & 63;
  const int w = __builtin_amdgcn_readfirstlane(t >> 6);   // wave 0..3 (uniform)

  // ---- staging addressing (per thread: 2x 16B = elements E = i*1024 + t*4)
  const int px_st = (t & 31) * 4;                 // 0..124, 16B-aligned group
  const int cc0 = t >> 5;                         // 0..7 (i adds 8)
  const int gp_st = pxt * 128 + px_st;
  const int gpc = (gp_st <= NPIX - 4) ? gp_st : (NPIX - 4);
  const int b_st = gpc / PPB, pb_st = gpc - b_st * PPB;   // 16B never straddles batch (PPB%4==0)
  const float* srcA0 = F + ((size_t)b_st * CINv + ks * 128 + cc0) * PPB + pb_st;
  const float* srcA1 = srcA0 + (size_t)8 * PPB;   // cc + 8
  // LDS dest (wave-uniform base; HW adds lane*16B): buf + i*4096B + w*1024B
  float* dstW = Abuf + w * 256;                   // floats

  // ---- compute addressing
  const int p2 = (t & 63) * 2;                    // px pair 0..126
  const float* wB = Wm + (size_t)(ogg * 32 + w * 8) * CINv + ks * 128;

  float acc[8][2];
#pragma unroll
  for (int j = 0; j < 8; ++j) { acc[j][0] = 0.f; acc[j][1] = 0.f; }

#define STAGE(s, buf)                                                         \
  {                                                                           \
    const size_t koff = (size_t)(s) * 16 * PPB;                               \
    async_copy16(srcA0 + koff, dstW + (buf) * 2048);                          \
    async_copy16(srcA1 + koff, dstW + (buf) * 2048 + 1024);                   \
  }

  STAGE(0, 0)
  __syncthreads();

  int cur = 0;
#pragma unroll 1
  for (int s = 0; s < 8; ++s) {
    if (s < 7) STAGE(s + 1, cur ^ 1)
    const float* Ab = Abuf + cur * 2048;
    const float* wS = wB + s * 16;
#pragma unroll
    for (int kq = 0; kq < 4; ++kq) {
      float4 wq[8];
#pragma unroll
      for (int j = 0; j < 8; ++j)
        wq[j] = *reinterpret_cast<const float4*>(wS + j * CINv + kq * 4);
#pragma unroll
      for (int kk = 0; kk < 4; ++kk) {
        const float2 a =
            *reinterpret_cast<const float2*>(Ab + (kq * 4 + kk) * 128 + p2);
        const float* wqf = reinterpret_cast<const float*>(wq);
#pragma unroll
        for (int j = 0; j < 8; ++j) {
          const float wv = wqf[j * 4 + kk];
          acc[j][0] = fmaf(a.x, wv, acc[j][0]);
          acc[j][1] = fmaf(a.y, wv, acc[j][1]);
        }
      }
    }
    __syncthreads();   // drains the STAGE's vmcnt + protects buf reuse
    cur ^= 1;
  }
#undef STAGE

  const int gp0 = pxt * 128 + p2;
  if (gp0 <= NPIX - 2) {
#pragma unroll
    for (int j = 0; j < 8; ++j) {
      float2 v;
      v.x = acc[j][0]; v.y = acc[j][1];
      *reinterpret_cast<float2*>(
          P + (size_t)(ks * 64 + ogg * 32 + w * 8 + j) * NPIX + gp0) = v;
    }
  }
}

__global__ __launch_bounds__(256) void k_gemm(const float* __restrict__ f1,
                                              const float* __restrict__ f2,
                                              const float* __restrict__ w1,
                                              const float* __restrict__ w2,
                                              float* __restrict__ ws) {
  __shared__ float Abuf[2 * 2048];
  // bid = ogg*752 + f ; family f = (pxt,ks); ogg-pair shares A via same XCD.
  const int bid = blockIdx.x;          // 0..1503
  const int ogg = bid / 752;           // 0..1
  const int f = bid - ogg * 752;       // 0..751

  if (f < 600) {
    gemm_tile<PPB1, NP1>(f1, w1, ws + WS_P1, f >> 2, ogg, f & 3, Abuf);
  } else {
    const int g = f - 600;             // 0..151  (38 px-tiles x 4 ks)
    gemm_tile<PPB2, NP2>(f2, w2, ws + WS_P2, g >> 2, ogg, g & 3, Abuf);
  }
}

// ---------------------------------------------------------------------------
// Kernel 2: sum 4 K-slices -> relu+bias, add x2-upsampled branch2 (slice-
// summed at the 4 taps), then 64->11 GEMM per pixel -> z (coarse logits).
// Grid: 600 blocks x 256 thr; 32 px per block; thread = (px, channel-octet).
// Block 0 also inits the bbx shard accumulators (runs before k_up_softmax).
// ---------------------------------------------------------------------------
__global__ __launch_bounds__(256) void k_combine_z(float* __restrict__ ws,
                                                   const float* __restrict__ b1,
                                                   const float* __restrict__ b2,
                                                   const float* __restrict__ w3,
                                                   const float* __restrict__ b3) {
  __shared__ float inter[64 * 32];  // [ch][px]
  __shared__ float w3s[NCl * HIDv];
  const int t = threadIdx.x;

  if (blockIdx.x == 0) {  // init bbx shards: 64*36 entries x 8 ints
    int* sh = (int*)(ws + WS_BBX);
    for (int i = t; i < NSHARD * 36 * 8; i += 256) {
      int f = i & 7;
      sh[i] = (f == 0 || f >= 5) ? 0
            : ((f == 1 || f == 3) ? 0x7fffffff : (int)0x80000000);
    }
  }
  for (int e = t; e < NCl * HIDv; e += 256) w3s[e] = w3[e];

  const int pxl = t & 31;
  const int qi = t >> 5;  // 0..7, 8 channels each
  const int gp = blockIdx.x * 32 + pxl;
  const int b = gp / PPB1, pb = gp - b * PPB1;
  const int y = pb / w1v, x = pb - y * w1v;

  // x2 bilinear (half-pixel, edge clamp)
  const float sx = x * 0.5f - 0.25f;
  const float x0f = floorf(sx);
  const float fx = sx - x0f;
  const int ix0 = iclamp((int)x0f, 0, w2v - 1);
  const int ix1 = iclamp((int)x0f + 1, 0, w2v - 1);
  const float sy = y * 0.5f - 0.25f;
  const float y0f = floorf(sy);
  const float fy = sy - y0f;
  const int iy0 = iclamp((int)y0f, 0, h2v - 1);
  const int iy1 = iclamp((int)y0f + 1, 0, h2v - 1);

  const float* p1 = ws + WS_P1;
  const float* p2 = ws + WS_P2;
  const int base2 = b * PPB2;
  const int i00 = base2 + iy0 * w2v + ix0;
  const int i01 = base2 + iy0 * w2v + ix1;
  const int i10 = base2 + iy1 * w2v + ix0;
  const int i11 = base2 + iy1 * w2v + ix1;

#pragma unroll
  for (int cc = 0; cc < 8; ++cc) {
    const int ch = qi * 8 + cc;
    float v = b1[ch];
#pragma unroll
    for (int s = 0; s < 4; ++s)
      v += p1[(size_t)(s * 64 + ch) * NP1 + gp];
    v = fmaxf(v, 0.f);
    float t00 = b2[ch], t01 = t00, t10 = t00, t11 = t00;
#pragma unroll
    for (int s = 0; s < 4; ++s) {
      const float* ps = p2 + (size_t)(s * 64 + ch) * NP2;
      t00 += ps[i00]; t01 += ps[i01]; t10 += ps[i10]; t11 += ps[i11];
    }
    const float v00 = fmaxf(t00, 0.f), v01 = fmaxf(t01, 0.f);
    const float v10 = fmaxf(t10, 0.f), v11 = fmaxf(t11, 0.f);
    const float top = v00 + fx * (v01 - v00);
    const float bot = v10 + fx * (v11 - v10);
    v += top + fy * (bot - top);
    inter[ch * 32 + pxl] = v;
  }
  __syncthreads();

  // z = W3 * inter + b3: out o = qi, plus o = qi+8 for qi < 3
  float* z = ws + WS_Z;
  {
    float a = b3[qi];
#pragma unroll
    for (int ch = 0; ch < 64; ++ch)
      a = fmaf(inter[ch * 32 + pxl], w3s[qi * HIDv + ch], a);
    z[((size_t)b * NCl + qi) * PPB1 + pb] = a;
  }
  if (qi < 3) {
    const int o = qi + 8;
    float a = b3[o];
#pragma unroll
    for (int ch = 0; ch < 64; ++ch)
      a = fmaf(inter[ch * 32 + pxl], w3s[o * HIDv + ch], a);
    z[((size_t)b * NCl + o) * PPB1 + pb] = a;
  }
}

// ---------------------------------------------------------------------------
// Kernel 3: x8 bilinear of z + relu + softmax + argmax + in-wave ballot bbx.
// Block = 128x2 fine tile, grid 4800; 1 px/thread (lg[11] stays in regs).
// ---------------------------------------------------------------------------
__global__ __launch_bounds__(256) void k_up_softmax(const float* __restrict__ ws,
                                                    float* __restrict__ out,
                                                    int* __restrict__ shards) {
  constexpr int ZR = 3, ZC = 18, ZN = NCl * ZR * ZC;  // 594
  __shared__ float zt[ZN];
  __shared__ int sB[4][9][4];
  const int t = threadIdx.x;
  const int tile = blockIdx.x;
  const int tx = tile % 5;
  const int ty = (tile / 5) % 240;
  const int b  = tile / 1200;
  const int base_x = tx * 16 - 1;
  const int row0 = ty * 2;
  const int base_y = (int)floorf((row0 + 0.5f) * 0.125f - 0.5f);

  // stage z tile (edge-clamped)
  const float* zb = ws + WS_Z + (size_t)b * NCl * PPB1;
  for (int e = t; e < ZN; e += 256) {
    int ch = e / (ZR * ZC);
    int rc = e % (ZR * ZC);
    int row = rc / ZC, col = rc % ZC;
    int gr = iclamp(base_y + row, 0, h1v - 1);
    int gc = iclamp(base_x + col, 0, w1v - 1);
    zt[e] = zb[(size_t)ch * PPB1 + gr * w1v + gc];
  }
  __syncthreads();

  const int x  = t & 127;
  const int rr = t >> 7;
  const int X = tx * 128 + x;
  const int Y = row0 + rr;

  const float sy = (Y + 0.5f) * 0.125f - 0.5f;
  const int y0g = (int)floorf(sy);
  const float fy = sy - (float)y0g;
  const int lry = y0g - base_y;                       // 0 or 1
  const int lcx = (2 * x + 9) >> 4;                   // 0..16
  const float fx = (float)(2 * x - 7) * 0.0625f + 1.0f - (float)lcx;

  float lg[NCl];
  float m = -1.f;
  int bi = 0;
#pragma unroll
  for (int c = 0; c < NCl; ++c) {
    const int base = c * (ZR * ZC) + lry * ZC + lcx;
    float v00 = zt[base],      v01 = zt[base + 1];
    float v10 = zt[base + ZC], v11 = zt[base + ZC + 1];
    float l0 = v00 + fy * (v10 - v00);
    float l1 = v01 + fy * (v11 - v01);
    float v = fmaxf(l0 + fx * (l1 - l0), 0.f);        // relu(logit)
    lg[c] = v;
    if (v > m) { m = v; bi = c; }                     // first-index tiebreak
  }

  float s = 0.f;
#pragma unroll
  for (int c = 0; c < NCl; ++c) {
    float e = __expf(lg[c] - m);
    lg[c] = e;
    s += e;
  }
  const float inv = __builtin_amdgcn_rcpf(s);

  const size_t r = (size_t)Y * Wf + X;
  float* prob = out + (size_t)b * NCl * PPBF;
#pragma unroll
  for (int c = 0; c < NCl; ++c)
    prob[(size_t)c * PPBF + r] = lg[c] * inv;
  out[OUT_SEG + (size_t)b * PPBF + r] = (float)bi;

  // --- bbx via wave ballot (wave = 64 contiguous x in row Y) ---
  const int lane = t & 63;
  const int wv = t >> 6;
  int cw[9], xn[9], xx[9];
#pragma unroll
  for (int c = 1; c <= 9; ++c) {
    unsigned long long msk = __ballot(bi == c);
    cw[c - 1] = (int)__popcll(msk);
    xn[c - 1] = msk ? (int)__builtin_ctzll(msk) : 0;
    xx[c - 1] = msk ? 63 - (int)__builtin_clzll(msk) : 0;
  }
  if (lane == 0) {   // lane0's X is the wave's base x
#pragma unroll
    for (int c = 0; c < 9; ++c) {
      sB[wv][c][0] = cw[c];
      sB[wv][c][1] = X + xn[c];
      sB[wv][c][2] = X + xx[c];
      sB[wv][c][3] = Y;
    }
  }
  __syncthreads();
  if (t < 9) {
    int C = 0, mn = 0x7fffffff, mx = -1, yn = 0x7fffffff, yx = -1;
#pragma unroll
    for (int w2 = 0; w2 < 4; ++w2) {
      int cc = sB[w2][t][0];
      if (cc) {
        C += cc;
        mn = min(mn, sB[w2][t][1]); mx = max(mx, sB[w2][t][2]);
        yn = min(yn, sB[w2][t][3]); yx = max(yx, sB[w2][t][3]);
      }
    }
    if (C) {
      int* e = shards + (((tile & (NSHARD - 1)) * 36) + b * 9 + t) * 8;
      atomicAdd(e + 0, C);
      atomicMin(e + 1, mn);
      atomicMax(e + 2, mx);
      atomicMin(e + 3, yn);
      atomicMax(e + 4, yx);
    }
  }
}

// ---------------------------------------------------------------------------
// Kernel 4: reduce shards, finalize bbx rows (36 x 6), THRESH = 100.
// ---------------------------------------------------------------------------
__global__ void k_bbx_final(const int* __restrict__ sh, float* __restrict__ out) {
  const int t = threadIdx.x;
  if (t >= 36) return;
  int C = 0, xn = 0x7fffffff, xx = -1, yn = 0x7fffffff, yx = -1;
  for (int s = 0; s < NSHARD; ++s) {
    const int* e = sh + (s * 36 + t) * 8;
    int c = e[0];
    if (c) {
      C += c;
      xn = min(xn, e[1]); xx = max(xx, e[2]);
      yn = min(yn, e[3]); yx = max(yx, e[4]);
    }
  }
  float* o = out + OUT_BBX + t * 6;
  if (C >= 100) {
    o[0] = (float)(t / 9);
    o[1] = (float)xn;
    o[2] = (float)yn;
    o[3] = (float)xx;
    o[4] = (float)yx;
    o[5] = (float)(t % 9 + 1);
  } else {
    for (int i = 0; i < 6; ++i) o[i] = -1.f;
  }
}

}  // namespace

extern "C" void kernel_launch(void* const* d_in, const int* in_sizes, int n_in,
                              void* d_out, int out_size, void* d_ws, size_t ws_size,
                              hipStream_t stream) {
  const float* f1 = (const float*)d_in[0];
  const float* f2 = (const float*)d_in[1];
  const float* w1 = (const float*)d_in[2];
  const float* b1 = (const float*)d_in[3];
  const float* w2 = (const float*)d_in[4];
  const float* b2 = (const float*)d_in[5];
  const float* w3 = (const float*)d_in[6];
  const float* b3 = (const float*)d_in[7];
  float* out = (float*)d_out;
  float* ws = (float*)d_ws;

  hipLaunchKernelGGL(k_gemm, dim3(1504), dim3(256), 0, stream, f1, f2, w1, w2, ws);
  hipLaunchKernelGGL(k_combine_z, dim3(600), dim3(256), 0, stream, ws, b1, b2, w3, b3);
  hipLaunchKernelGGL(k_up_softmax, dim3(4800), dim3(256), 0, stream, ws, out,
                     (int*)(ws + WS_BBX));
  hipLaunchKernelGGL(k_bbx_final, dim3(1), dim3(64), 0, stream,
                     (const int*)(ws + WS_BBX), out);
}

// Round 11
// 78.877 us; speedup vs baseline: 1.0743x; 1.0037x over previous
//
#include <hip/hip_runtime.h>

#define DEVINL __device__ __forceinline__

namespace {

constexpr int NB   = 4;
constexpr int CINv = 512;
constexpr int HIDv = 64;
constexpr int NCl  = 11;   // NC+1 output channels
constexpr int h1v = 60, w1v = 80;
constexpr int h2v = 30, w2v = 40;
constexpr int Hf = 480, Wf = 640;
constexpr int PPB1 = h1v * w1v;     // 4800 coarse px / batch
constexpr int PPB2 = h2v * w2v;     // 1200
constexpr int NP1 = NB * PPB1;      // 19200
constexpr int NP2 = NB * PPB2;      // 4800
constexpr int PPBF = Hf * Wf;       // 307200 fine px / batch
constexpr int NPF = NB * PPBF;      // 1228800
constexpr int NSHARD = 64;          // bbx accumulator shards

// workspace layout (float elements). 4 K-slices of partials per conv.
constexpr size_t WS_P1  = 0;                               // 4*64*19200
constexpr size_t WS_P2  = WS_P1 + 4ull * HIDv * NP1;       // 4*64*4800
constexpr size_t WS_Z   = WS_P2 + 4ull * HIDv * NP2;       // 4*11*4800
constexpr size_t WS_BBX = WS_Z + (size_t)NB * NCl * PPB1;  // 64 shards x 36 x 8 ints

// output layout (float elements)
constexpr size_t OUT_SEG = (size_t)NB * NCl * PPBF;  // 13,516,800
constexpr size_t OUT_BBX = OUT_SEG + (size_t)NPF;    // +1,228,800

DEVINL int iclamp(int v, int lo, int hi) { return v < lo ? lo : (v > hi ? hi : v); }

DEVINL void async_copy16(const float* g_src, float* lds_dst) {
  __builtin_amdgcn_global_load_lds(
      (const __attribute__((address_space(1))) unsigned int*)g_src,
      (__attribute__((address_space(3))) unsigned int*)lds_dst, 16, 0, 0);
}

// ---------------------------------------------------------------------------
// Kernel 1: 1x1 convs, K-split GEMM, LDS-staged A via global_load_lds.
// v7: TWO DISTINCT __shared__ buffers referenced statically (2x-unrolled
// body).  Round-10 used one Abuf[2][2048] indexed by runtime `cur`; LLVM
// models global_load_lds as an LDS write and, unable to disambiguate it from
// the compute's ds_reads within ONE LDS object, emits s_waitcnt vmcnt(0)
// BEFORE the first ds_read -> every step serialized stage-wait -> compute
// (~36us).  With distinct objects A0/A1, object-based AA proves
// ds_read(A0) !alias global_load_lds(A1); the only vmcnt(0) sits inside
// __syncthreads() AFTER compute, where the DMA has already landed under the
// 512-cycle FMA phase (m97-verified overlap pattern).
// Block = 256 thr (4 waves) = 128 px x 32 outs x 128 K-slice; BK=16.
//   A: [cc][128 px] in LDS (8 KB x 2); ds_read_b64 lane-contiguous (no
//      bank conflicts).  W: uniform s_load, consumed inline (SGPR side).
// Grid 1504 = 5.9 blocks/CU (23.5 waves/CU); A-sharing ogg-pair at bid f
// and f+752 (752%8==0 -> same XCD L2; FETCH 25MB < 49MB inputs confirms).
// ---------------------------------------------------------------------------
template <int PPB, int NPIX>
DEVINL void gemm_tile(const float* __restrict__ F, const float* __restrict__ Wm,
                      float* __restrict__ P, int pxt, int ogg, int ks,
                      float* __restrict__ A0, float* __restrict__ A1) {
  const int t = threadIdx.x;
  const int w = __builtin_amdgcn_readfirstlane(t >> 6);   // wave 0..3 (uniform)

  // ---- staging addressing (per thread: 2x 16B; verified element-exact:
  // copy i of thread t=(w,l) writes A[cc = 2w + (l>>5) + 8i][px=(l&31)*4 ..]
  const int px_st = (t & 31) * 4;
  const int cc0 = t >> 5;                         // 0..7
  const int gp_st = pxt * 128 + px_st;
  const int gpc = (gp_st <= NPIX - 4) ? gp_st : (NPIX - 4);
  const int b_st = gpc / PPB, pb_st = gpc - b_st * PPB;   // 16B never straddles batch
  const float* srcA0 = F + ((size_t)b_st * CINv + ks * 128 + cc0) * PPB + pb_st;
  const float* srcA1 = srcA0 + (size_t)8 * PPB;   // cc + 8

  // ---- compute addressing
  const int p2 = (t & 63) * 2;                    // px pair 0..126
  const float* wB = Wm + (size_t)(ogg * 32 + w * 8) * CINv + ks * 128;

  float acc[8][2];
#pragma unroll
  for (int j = 0; j < 8; ++j) { acc[j][0] = 0.f; acc[j][1] = 0.f; }

#define STAGE(s, DST)                                                         \
  {                                                                           \
    const size_t koff = (size_t)(s) * 16 * PPB;                               \
    async_copy16(srcA0 + koff, (DST) + w * 256);                              \
    async_copy16(srcA1 + koff, (DST) + w * 256 + 1024);                       \
  }

#define COMPUTE(AB, s)                                                        \
  {                                                                           \
    const float* wS = wB + (s) * 16;                                          \
    _Pragma("unroll")                                                         \
    for (int kq = 0; kq < 4; ++kq) {                                          \
      float4 wq[8];                                                           \
      _Pragma("unroll")                                                       \
      for (int j = 0; j < 8; ++j)                                             \
        wq[j] = *reinterpret_cast<const float4*>(wS + j * CINv + kq * 4);     \
      _Pragma("unroll")                                                       \
      for (int kk = 0; kk < 4; ++kk) {                                        \
        const float2 a =                                                      \
            *reinterpret_cast<const float2*>((AB) + (kq * 4 + kk) * 128 + p2);\
        const float* wqf = reinterpret_cast<const float*>(wq);                \
        _Pragma("unroll")                                                     \
        for (int j = 0; j < 8; ++j) {                                         \
          const float wv = wqf[j * 4 + kk];                                   \
          acc[j][0] = fmaf(a.x, wv, acc[j][0]);                               \
          acc[j][1] = fmaf(a.y, wv, acc[j][1]);                               \
        }                                                                     \
      }                                                                       \
    }                                                                         \
  }

  STAGE(0, A0)
  __syncthreads();

#pragma unroll 1
  for (int s = 0; s < 8; s += 2) {
    if (s < 7) STAGE(s + 1, A1)      // stage odd step into A1
    COMPUTE(A0, s)                   // compute even step from A0 (distinct obj)
    __syncthreads();                 // drains: stage(s+1) landed; A0 free
    if (s + 2 < 8) STAGE(s + 2, A0)  // stage next even step into A0
    COMPUTE(A1, s + 1)               // compute odd step from A1
    __syncthreads();
  }
#undef STAGE
#undef COMPUTE

  const int gp0 = pxt * 128 + p2;
  if (gp0 <= NPIX - 2) {
#pragma unroll
    for (int j = 0; j < 8; ++j) {
      float2 v;
      v.x = acc[j][0]; v.y = acc[j][1];
      *reinterpret_cast<float2*>(
          P + (size_t)(ks * 64 + ogg * 32 + w * 8 + j) * NPIX + gp0) = v;
    }
  }
}

__global__ __launch_bounds__(256) void k_gemm(const float* __restrict__ f1,
                                              const float* __restrict__ f2,
                                              const float* __restrict__ w1,
                                              const float* __restrict__ w2,
                                              float* __restrict__ ws) {
  __shared__ float A0[2048];   // two DISTINCT objects -> alias-disjoint
  __shared__ float A1[2048];
  // bid = ogg*752 + f ; family f = (pxt,ks); ogg-pair shares A via same XCD.
  const int bid = blockIdx.x;          // 0..1503
  const int ogg = bid / 752;           // 0..1
  const int f = bid - ogg * 752;       // 0..751

  if (f < 600) {
    gemm_tile<PPB1, NP1>(f1, w1, ws + WS_P1, f >> 2, ogg, f & 3, A0, A1);
  } else {
    const int g = f - 600;             // 0..151  (38 px-tiles x 4 ks)
    gemm_tile<PPB2, NP2>(f2, w2, ws + WS_P2, g >> 2, ogg, g & 3, A0, A1);
  }
}

// ---------------------------------------------------------------------------
// Kernel 2: sum 4 K-slices -> relu+bias, add x2-upsampled branch2 (slice-
// summed at the 4 taps), then 64->11 GEMM per pixel -> z (coarse logits).
// Grid: 600 blocks x 256 thr; 32 px per block; thread = (px, channel-octet).
// Block 0 also inits the bbx shard accumulators (runs before k_up_softmax).
// ---------------------------------------------------------------------------
__global__ __launch_bounds__(256) void k_combine_z(float* __restrict__ ws,
                                                   const float* __restrict__ b1,
                                                   const float* __restrict__ b2,
                                                   const float* __restrict__ w3,
                                                   const float* __restrict__ b3) {
  __shared__ float inter[64 * 32];  // [ch][px]
  __shared__ float w3s[NCl * HIDv];
  const int t = threadIdx.x;

  if (blockIdx.x == 0) {  // init bbx shards: 64*36 entries x 8 ints
    int* sh = (int*)(ws + WS_BBX);
    for (int i = t; i < NSHARD * 36 * 8; i += 256) {
      int f = i & 7;
      sh[i] = (f == 0 || f >= 5) ? 0
            : ((f == 1 || f == 3) ? 0x7fffffff : (int)0x80000000);
    }
  }
  for (int e = t; e < NCl * HIDv; e += 256) w3s[e] = w3[e];

  const int pxl = t & 31;
  const int qi = t >> 5;  // 0..7, 8 channels each
  const int gp = blockIdx.x * 32 + pxl;
  const int b = gp / PPB1, pb = gp - b * PPB1;
  const int y = pb / w1v, x = pb - y * w1v;

  // x2 bilinear (half-pixel, edge clamp)
  const float sx = x * 0.5f - 0.25f;
  const float x0f = floorf(sx);
  const float fx = sx - x0f;
  const int ix0 = iclamp((int)x0f, 0, w2v - 1);
  const int ix1 = iclamp((int)x0f + 1, 0, w2v - 1);
  const float sy = y * 0.5f - 0.25f;
  const float y0f = floorf(sy);
  const float fy = sy - y0f;
  const int iy0 = iclamp((int)y0f, 0, h2v - 1);
  const int iy1 = iclamp((int)y0f + 1, 0, h2v - 1);

  const float* p1 = ws + WS_P1;
  const float* p2 = ws + WS_P2;
  const int base2 = b * PPB2;
  const int i00 = base2 + iy0 * w2v + ix0;
  const int i01 = base2 + iy0 * w2v + ix1;
  const int i10 = base2 + iy1 * w2v + ix0;
  const int i11 = base2 + iy1 * w2v + ix1;

#pragma unroll
  for (int cc = 0; cc < 8; ++cc) {
    const int ch = qi * 8 + cc;
    float v = b1[ch];
#pragma unroll
    for (int s = 0; s < 4; ++s)
      v += p1[(size_t)(s * 64 + ch) * NP1 + gp];
    v = fmaxf(v, 0.f);
    float t00 = b2[ch], t01 = t00, t10 = t00, t11 = t00;
#pragma unroll
    for (int s = 0; s < 4; ++s) {
      const float* ps = p2 + (size_t)(s * 64 + ch) * NP2;
      t00 += ps[i00]; t01 += ps[i01]; t10 += ps[i10]; t11 += ps[i11];
    }
    const float v00 = fmaxf(t00, 0.f), v01 = fmaxf(t01, 0.f);
    const float v10 = fmaxf(t10, 0.f), v11 = fmaxf(t11, 0.f);
    const float top = v00 + fx * (v01 - v00);
    const float bot = v10 + fx * (v11 - v10);
    v += top + fy * (bot - top);
    inter[ch * 32 + pxl] = v;
  }
  __syncthreads();

  // z = W3 * inter + b3: out o = qi, plus o = qi+8 for qi < 3
  float* z = ws + WS_Z;
  {
    float a = b3[qi];
#pragma unroll
    for (int ch = 0; ch < 64; ++ch)
      a = fmaf(inter[ch * 32 + pxl], w3s[qi * HIDv + ch], a);
    z[((size_t)b * NCl + qi) * PPB1 + pb] = a;
  }
  if (qi < 3) {
    const int o = qi + 8;
    float a = b3[o];
#pragma unroll
    for (int ch = 0; ch < 64; ++ch)
      a = fmaf(inter[ch * 32 + pxl], w3s[o * HIDv + ch], a);
    z[((size_t)b * NCl + o) * PPB1 + pb] = a;
  }
}

// ---------------------------------------------------------------------------
// Kernel 3: x8 bilinear of z + relu + softmax + argmax + in-wave ballot bbx.
// Block = 128x2 fine tile, grid 4800; 1 px/thread (lg[11] stays in regs).
// ---------------------------------------------------------------------------
__global__ __launch_bounds__(256) void k_up_softmax(const float* __restrict__ ws,
                                                    float* __restrict__ out,
                                                    int* __restrict__ shards) {
  constexpr int ZR = 3, ZC = 18, ZN = NCl * ZR * ZC;  // 594
  __shared__ float zt[ZN];
  __shared__ int sB[4][9][4];
  const int t = threadIdx.x;
  const int tile = blockIdx.x;
  const int tx = tile % 5;
  const int ty = (tile / 5) % 240;
  const int b  = tile / 1200;
  const int base_x = tx * 16 - 1;
  const int row0 = ty * 2;
  const int base_y = (int)floorf((row0 + 0.5f) * 0.125f - 0.5f);

  // stage z tile (edge-clamped)
  const float* zb = ws + WS_Z + (size_t)b * NCl * PPB1;
  for (int e = t; e < ZN; e += 256) {
    int ch = e / (ZR * ZC);
    int rc = e % (ZR * ZC);
    int row = rc / ZC, col = rc % ZC;
    int gr = iclamp(base_y + row, 0, h1v - 1);
    int gc = iclamp(base_x + col, 0, w1v - 1);
    zt[e] = zb[(size_t)ch * PPB1 + gr * w1v + gc];
  }
  __syncthreads();

  const int x  = t & 127;
  const int rr = t >> 7;
  const int X = tx * 128 + x;
  const int Y = row0 + rr;

  const float sy = (Y + 0.5f) * 0.125f - 0.5f;
  const int y0g = (int)floorf(sy);
  const float fy = sy - (float)y0g;
  const int lry = y0g - base_y;                       // 0 or 1
  const int lcx = (2 * x + 9) >> 4;                   // 0..16
  const float fx = (float)(2 * x - 7) * 0.0625f + 1.0f - (float)lcx;

  float lg[NCl];
  float m = -1.f;
  int bi = 0;
#pragma unroll
  for (int c = 0; c < NCl; ++c) {
    const int base = c * (ZR * ZC) + lry * ZC + lcx;
    float v00 = zt[base],      v01 = zt[base + 1];
    float v10 = zt[base + ZC], v11 = zt[base + ZC + 1];
    float l0 = v00 + fy * (v10 - v00);
    float l1 = v01 + fy * (v11 - v01);
    float v = fmaxf(l0 + fx * (l1 - l0), 0.f);        // relu(logit)
    lg[c] = v;
    if (v > m) { m = v; bi = c; }                     // first-index tiebreak
  }

  float s = 0.f;
#pragma unroll
  for (int c = 0; c < NCl; ++c) {
    float e = __expf(lg[c] - m);
    lg[c] = e;
    s += e;
  }
  const float inv = __builtin_amdgcn_rcpf(s);

  const size_t r = (size_t)Y * Wf + X;
  float* prob = out + (size_t)b * NCl * PPBF;
#pragma unroll
  for (int c = 0; c < NCl; ++c)
    prob[(size_t)c * PPBF + r] = lg[c] * inv;
  out[OUT_SEG + (size_t)b * PPBF + r] = (float)bi;

  // --- bbx via wave ballot (wave = 64 contiguous x in row Y) ---
  const int lane = t & 63;
  const int wv = t >> 6;
  int cw[9], xn[9], xx[9];
#pragma unroll
  for (int c = 1; c <= 9; ++c) {
    unsigned long long msk = __ballot(bi == c);
    cw[c - 1] = (int)__popcll(msk);
    xn[c - 1] = msk ? (int)__builtin_ctzll(msk) : 0;
    xx[c - 1] = msk ? 63 - (int)__builtin_clzll(msk) : 0;
  }
  if (lane == 0) {   // lane0's X is the wave's base x
#pragma unroll
    for (int c = 0; c < 9; ++c) {
      sB[wv][c][0] = cw[c];
      sB[wv][c][1] = X + xn[c];
      sB[wv][c][2] = X + xx[c];
      sB[wv][c][3] = Y;
    }
  }
  __syncthreads();
  if (t < 9) {
    int C = 0, mn = 0x7fffffff, mx = -1, yn = 0x7fffffff, yx = -1;
#pragma unroll
    for (int w2 = 0; w2 < 4; ++w2) {
      int cc = sB[w2][t][0];
      if (cc) {
        C += cc;
        mn = min(mn, sB[w2][t][1]); mx = max(mx, sB[w2][t][2]);
        yn = min(yn, sB[w2][t][3]); yx = max(yx, sB[w2][t][3]);
      }
    }
    if (C) {
      int* e = shards + (((tile & (NSHARD - 1)) * 36) + b * 9 + t) * 8;
      atomicAdd(e + 0, C);
      atomicMin(e + 1, mn);
      atomicMax(e + 2, mx);
      atomicMin(e + 3, yn);
      atomicMax(e + 4, yx);
    }
  }
}

// ---------------------------------------------------------------------------
// Kernel 4: reduce shards, finalize bbx rows (36 x 6), THRESH = 100.
// ---------------------------------------------------------------------------
__global__ void k_bbx_final(const int* __restrict__ sh, float* __restrict__ out) {
  const int t = threadIdx.x;
  if (t >= 36) return;
  int C = 0, xn = 0x7fffffff, xx = -1, yn = 0x7fffffff, yx = -1;
  for (int s = 0; s < NSHARD; ++s) {
    const int* e = sh + (s * 36 + t) * 8;
    int c = e[0];
    if (c) {
      C += c;
      xn = min(xn, e[1]); xx = max(xx, e[2]);
      yn = min(yn, e[3]); yx = max(yx, e[4]);
    }
  }
  float* o = out + OUT_BBX + t * 6;
  if (C >= 100) {
    o[0] = (float)(t / 9);
    o[1] = (float)xn;
    o[2] = (float)yn;
    o[3] = (float)xx;
    o[4] = (float)yx;
    o[5] = (float)(t % 9 + 1);
  } else {
    for (int i = 0; i < 6; ++i) o[i] = -1.f;
  }
}

}  // namespace

extern "C" void kernel_launch(void* const* d_in, const int* in_sizes, int n_in,
                              void* d_out, int out_size, void* d_ws, size_t ws_size,
                              hipStream_t stream) {
  const float* f1 = (const float*)d_in[0];
  const float* f2 = (const float*)d_in[1];
  const float* w1 = (const float*)d_in[2];
  const float* b1 = (const float*)d_in[3];
  const float* w2 = (const float*)d_in[4];
  const float* b2 = (const float*)d_in[5];
  const float* w3 = (const float*)d_in[6];
  const float* b3 = (const float*)d_in[7];
  float* out = (float*)d_out;
  float* ws = (float*)d_ws;

  hipLaunchKernelGGL(k_gemm, dim3(1504), dim3(256), 0, stream, f1, f2, w1, w2, ws);
  hipLaunchKernelGGL(k_combine_z, dim3(600), dim3(256), 0, stream, ws, b1, b2, w3, b3);
  hipLaunchKernelGGL(k_up_softmax, dim3(4800), dim3(256), 0, stream, ws, out,
                     (int*)(ws + WS_BBX));
  hipLaunchKernelGGL(k_bbx_final, dim3(1), dim3(64), 0, stream,
                     (const int*)(ws + WS_BBX), out);
}